// Round 4
// baseline (417.154 us; speedup 1.0000x reference)
//
#include <hip/hip_runtime.h>
#include <hip/hip_bf16.h>
#include <stdint.h>
#include <stddef.h>

// ---------------------------------------------------------------------------
// RingAttentionLayer on MI355X (gfx950)
// R4: attention restructured: 32 q-rows/wave (2x16q subtiles sharing K/V
// fragment reads -> ~40% less LDS traffic), K-range split x2 (flash-decoding)
// for 4 co-resident 40KB blocks/CU, exact partial merge kernel. gemm_o BK=128.
// ---------------------------------------------------------------------------

typedef __attribute__((ext_vector_type(8))) short bf16x8;   // 8 bf16 = 4 VGPRs
typedef __attribute__((ext_vector_type(4))) float f32x4;

#define MFMA_BF16(a, b, c) __builtin_amdgcn_mfma_f32_16x16x32_bf16((a), (b), (c), 0, 0, 0)

__device__ __forceinline__ void load16_lds(const void* g, void* l) {
  __builtin_amdgcn_global_load_lds((const __attribute__((address_space(1))) void*)g,
                                   (__attribute__((address_space(3))) void*)l,
                                   16, 0, 0);
}

__device__ __forceinline__ unsigned short f2bf(float x) {
  union { __hip_bfloat16 b; unsigned short u; } cv;
  cv.b = __float2bfloat16(x);
  return cv.u;
}
__device__ __forceinline__ float bf2f(unsigned short u) {
  union { unsigned int i; float f; } cv;
  cv.i = ((unsigned int)u) << 16;
  return cv.f;
}

// ------------------------------- convert -----------------------------------
__global__ __launch_bounds__(256) void cvt_all(
    const float4* __restrict__ s0, const float4* __restrict__ s1,
    const float4* __restrict__ s2, const float4* __restrict__ s3,
    const float4* __restrict__ s4,
    ushort4* __restrict__ d0, ushort4* __restrict__ d1,
    ushort4* __restrict__ d2, ushort4* __restrict__ d3,
    ushort4* __restrict__ d4) {
  const int seg = blockIdx.x >> 12;
  const int i = ((blockIdx.x & 4095) << 8) + threadIdx.x;
  const float4* s = seg == 0 ? s0 : seg == 1 ? s1 : seg == 2 ? s2 : seg == 3 ? s3 : s4;
  ushort4* d = seg == 0 ? d0 : seg == 1 ? d1 : seg == 2 ? d2 : seg == 3 ? d3 : d4;
  float4 v = s[i];
  ushort4 o;
  o.x = f2bf(v.x); o.y = f2bf(v.y); o.z = f2bf(v.z); o.w = f2bf(v.w);
  d[i] = o;
}

// --------------------------- fused QKV GEMM --------------------------------
// (unchanged from R2/R3: 128x128 tile, BK=64, chunk-XOR swizzle)
__global__ __launch_bounds__(256) void gemm_qkv(
    const unsigned short* __restrict__ A, const unsigned short* __restrict__ Bt,
    const float* __restrict__ qb, const float* __restrict__ kb,
    const float* __restrict__ vb,
    unsigned short* __restrict__ Qo, unsigned short* __restrict__ Ko,
    unsigned short* __restrict__ Vt) {
  __shared__ __align__(16) unsigned short sA[128 * 64];
  __shared__ __align__(16) unsigned short sB[128 * 64];
  const int tid = threadIdx.x;
  const int wave = tid >> 6, lane = tid & 63;
  const int quad = lane >> 4, l16 = lane & 15;
  const int wr = wave >> 1, wc = wave & 1;
  const int m0 = blockIdx.y << 7, n0 = blockIdx.x << 7;

  f32x4 acc[4][4] = {};

  for (int k0 = 0; k0 < 2048; k0 += 64) {
    __syncthreads();
#pragma unroll
    for (int t = 0; t < 4; t++) {
      const int i = t * 4 + wave;
      const int idx = i * 64 + lane;
      const int row = idx >> 3;
      const int c = (idx & 7) ^ (row & 7);
      load16_lds(A + (size_t)(m0 + row) * 2048 + k0 + c * 8, &sA[i * 512]);
      load16_lds(Bt + (size_t)(n0 + row) * 2048 + k0 + c * 8, &sB[i * 512]);
    }
    __syncthreads();
#pragma unroll
    for (int ks = 0; ks < 2; ks++) {
      bf16x8 af[4], bfr[4];
#pragma unroll
      for (int i = 0; i < 4; i++) {
        const int cs = ((ks * 4 + quad) ^ (l16 & 7)) << 3;
        af[i] = *(const bf16x8*)&sA[(wr * 64 + i * 16 + l16) * 64 + cs];
        bfr[i] = *(const bf16x8*)&sB[(wc * 64 + i * 16 + l16) * 64 + cs];
      }
#pragma unroll
      for (int mi = 0; mi < 4; mi++)
#pragma unroll
        for (int ni = 0; ni < 4; ni++)
          acc[mi][ni] = MFMA_BF16(af[mi], bfr[ni], acc[mi][ni]);
    }
  }

  const float qscale = 0.088388347648318447f * 1.4426950408889634f;  // scale*log2e
#pragma unroll
  for (int mi = 0; mi < 4; mi++) {
    const int row = m0 + wr * 64 + mi * 16 + quad * 4;
#pragma unroll
    for (int ni = 0; ni < 4; ni++) {
      const int col = n0 + wc * 64 + ni * 16 + l16;
#pragma unroll
      for (int r = 0; r < 4; r++) {
        const float v = acc[mi][ni][r];
        const int rr = row + r;
        if (col < 2048) {
          const int hh = col >> 7, d = col & 127;
          Qo[((size_t)hh * 2048 + rr) * 128 + d] = f2bf((v + qb[col]) * qscale);
        } else if (col < 4096) {
          const int f = col - 2048;
          const int hh = f >> 7, d = f & 127;
          Ko[((size_t)hh * 2048 + rr) * 128 + d] = f2bf(v + kb[f]);
        } else {
          const int f = col - 4096;
          const int hh = f >> 7, d = f & 127;
          Vt[((size_t)hh * 128 + d) * 2048 + rr] = f2bf(v + vb[f]);  // (H,D,S)
        }
      }
    }
  }
}

// ------------------------------ attention ----------------------------------
// grid (32 qtiles, 2 k-ranges, 16 heads), block = 128 threads (2 waves).
// Wave handles 32 q (2 subtiles of 16) over k-range [kr*1024, kr*1024+1024).
// Dual accumulators (masked/unmasked); partials written for exact merge.
__global__ __launch_bounds__(128, 2) void attn_fwd(
    const unsigned short* __restrict__ Q, const unsigned short* __restrict__ K,
    const unsigned short* __restrict__ V,   // (H, D, S) transposed
    unsigned short* __restrict__ oU, unsigned short* __restrict__ oM,
    float* __restrict__ stats) {            // mU,lU,mM,lM each [1024][64]
  const int qt = blockIdx.x, kr = blockIdx.y, h = blockIdx.z;
  const int b = (h * 2 + kr) * 32 + qt;
  const int tid = threadIdx.x;
  const int wave = tid >> 6, lane = tid & 63;
  const int quad = lane >> 4, l16 = lane & 15;

  __shared__ __align__(16) unsigned short sQK[64 * 128];  // Q staged, then K (overlay)
  __shared__ __align__(16) unsigned short sV[128 * 64];
  __shared__ __align__(16) unsigned short sP[2 * 2 * 1024];

  const unsigned short* Qh = Q + (size_t)h * 2048 * 128;
  const unsigned short* Kh = K + (size_t)h * 2048 * 128;
  const unsigned short* Vh = V + (size_t)h * 128 * 2048;

  // stage Q tile [64][128], chunk swizzle blk ^ (row&15)
  for (int c = wave; c < 16; c += 2) {
    const int rowc = lane >> 4;
    const int row = c * 4 + rowc;
    const int blk = (lane & 15) ^ (row & 15);
    load16_lds(Qh + (size_t)(qt * 64 + row) * 128 + blk * 8, &sQK[c * 512]);
  }
  __syncthreads();

  bf16x8 qf[2][4];
#pragma unroll
  for (int s = 0; s < 2; s++)
#pragma unroll
    for (int ds = 0; ds < 4; ds++)
      qf[s][ds] = *(const bf16x8*)&sQK[(wave * 32 + s * 16 + l16) * 128 +
                                       (((ds * 4 + quad) ^ l16) << 3)];

  float m1[2] = {-3.0e38f, -3.0e38f}, l1[2] = {0.f, 0.f};
  float m2[2] = {-3.0e38f, -3.0e38f}, l2[2] = {0.f, 0.f};
  f32x4 o1[2][8], o2[2][8];
#pragma unroll
  for (int s = 0; s < 2; s++)
#pragma unroll
    for (int j = 0; j < 8; j++) {
      o1[s][j] = f32x4{0.f, 0.f, 0.f, 0.f};
      o2[s][j] = f32x4{0.f, 0.f, 0.f, 0.f};
    }

  const int kbase = kr << 10;
  const int dloc = qt - (kr << 4);               // local diag tile index
  const bool inrange = (qt >> 4) == kr;

  auto softmax_update = [&](int sub, float& m, float& l, f32x4 (&o)[8],
                            const f32x4 (&stt)[4], bool masked, int k0) {
    const int qg = qt * 64 + wave * 32 + sub * 16 + l16;  // this lane's q column
    float t[4][4];
    float mx = -3.0e38f;
#pragma unroll
    for (int ni = 0; ni < 4; ni++)
#pragma unroll
      for (int r = 0; r < 4; r++) {
        float v = stt[ni][r];
        if (masked && (k0 + ni * 16 + quad * 4 + r > qg)) v = -3.0e38f;
        t[ni][r] = v;
        mx = fmaxf(mx, v);
      }
    mx = fmaxf(mx, __shfl_xor(mx, 16));
    mx = fmaxf(mx, __shfl_xor(mx, 32));
    const float mn = fmaxf(m, mx);
    const float al = exp2f(m - mn);
    unsigned short* sPw = &sP[(wave * 2 + sub) * 1024];
    float rs = 0.f;
#pragma unroll
    for (int ni = 0; ni < 4; ni++) {
      union { unsigned short u[4]; uint2 v; } pk;
#pragma unroll
      for (int r = 0; r < 4; r++) {
        const float p = exp2f(t[ni][r] - mn);
        rs += p;
        pk.u[r] = f2bf(p);
      }
      const int off =
          l16 * 64 + (((ni * 2 + (quad >> 1)) ^ (l16 & 7)) << 3) + ((quad & 1) << 2);
      *(uint2*)&sPw[off] = pk.v;
    }
    rs += __shfl_xor(rs, 16);
    rs += __shfl_xor(rs, 32);
    l = l * al + rs;
    m = mn;
#pragma unroll
    for (int r = 0; r < 4; r++) {
      const int src = (lane & 48) + quad * 4 + r;  // same quad, l16 = quad*4+r
      const float ab = __shfl(al, src);
#pragma unroll
      for (int j = 0; j < 8; j++) o[j][r] *= ab;
    }
  };

  auto pv_shared = [&](f32x4 (&oo)[2][8]) {
#pragma unroll
    for (int ks = 0; ks < 2; ks++) {
      const int cs = (((ks * 4 + quad) ^ (l16 & 7)) << 3);
      const bf16x8 pf0 = *(const bf16x8*)&sP[(wave * 2 + 0) * 1024 + l16 * 64 + cs];
      const bf16x8 pf1 = *(const bf16x8*)&sP[(wave * 2 + 1) * 1024 + l16 * 64 + cs];
#pragma unroll
      for (int j = 0; j < 8; j++) {
        const bf16x8 vf = *(const bf16x8*)&sV[(j * 16 + l16) * 64 + cs];
        oo[0][j] = MFMA_BF16(pf0, vf, oo[0][j]);
        oo[1][j] = MFMA_BF16(pf1, vf, oo[1][j]);
      }
    }
  };

  for (int kt = 0; kt < 16; kt++) {
    const int k0 = kbase + (kt << 6);
    __syncthreads();
    for (int c = wave; c < 16; c += 2) {
      {  // K tile [64][128] into sQK
        const int rowc = lane >> 4;
        const int row = c * 4 + rowc;
        const int blk = (lane & 15) ^ (row & 15);
        load16_lds(Kh + (size_t)(k0 + row) * 128 + blk * 8, &sQK[c * 512]);
      }
      {  // V tile [128 d][64 k]
        const int rowc = lane >> 3;
        const int row = c * 8 + rowc;
        const int blk = (lane & 7) ^ (rowc & 7);
        load16_lds(Vh + (size_t)row * 2048 + k0 + blk * 8, &sV[c * 512]);
      }
    }
    __syncthreads();

    // transposed scores, shared K-frag across both q-subtiles
    f32x4 st[2][4];
#pragma unroll
    for (int s = 0; s < 2; s++)
#pragma unroll
      for (int ni = 0; ni < 4; ni++) st[s][ni] = f32x4{0.f, 0.f, 0.f, 0.f};
#pragma unroll
    for (int ds = 0; ds < 4; ds++) {
#pragma unroll
      for (int ni = 0; ni < 4; ni++) {
        const bf16x8 kf =
            *(const bf16x8*)&sQK[(ni * 16 + l16) * 128 + (((ds * 4 + quad) ^ l16) << 3)];
        st[0][ni] = MFMA_BF16(kf, qf[0][ds], st[0][ni]);
        st[1][ni] = MFMA_BF16(kf, qf[1][ds], st[1][ni]);
      }
    }

    if (inrange && kt == dloc) {
#pragma unroll
      for (int s = 0; s < 2; s++) {
        m1[s] = m2[s]; l1[s] = l2[s];
#pragma unroll
        for (int j = 0; j < 8; j++) o1[s][j] = o2[s][j];
      }
      softmax_update(0, m1[0], l1[0], o1[0], st[0], true, k0);
      softmax_update(1, m1[1], l1[1], o1[1], st[1], true, k0);
      pv_shared(o1);
    }
    softmax_update(0, m2[0], l2[0], o2[0], st[0], false, k0);
    softmax_update(1, m2[1], l2[1], o2[1], st[1], false, k0);
    pv_shared(o2);
  }

  // out-of-range masked set: full-prefix (alias) or empty (already init)
  if (!inrange && kr == 0) {
#pragma unroll
    for (int s = 0; s < 2; s++) {
      m1[s] = m2[s]; l1[s] = l2[s];
#pragma unroll
      for (int j = 0; j < 8; j++) o1[s][j] = o2[s][j];
    }
  }

  // write partials
#pragma unroll
  for (int s = 0; s < 2; s++) {
    if (quad == 0) {
      const int q = wave * 32 + s * 16 + l16;
      stats[b * 64 + q] = m2[s];
      stats[65536 + b * 64 + q] = l2[s];
      stats[131072 + b * 64 + q] = m1[s];
      stats[196608 + b * 64 + q] = l1[s];
    }
#pragma unroll
    for (int j = 0; j < 8; j++)
#pragma unroll
      for (int r = 0; r < 4; r++) {
        const int q = wave * 32 + s * 16 + quad * 4 + r;
        const int d = j * 16 + l16;
        const size_t idx = ((size_t)b * 64 + q) * 128 + d;
        oU[idx] = f2bf(o2[s][j][r]);
        oM[idx] = f2bf(o1[s][j][r]);
      }
  }
}

// ------------------------------- merge -------------------------------------
// Exact flash merge of the 2 k-range partials + ring combine formula.
__global__ __launch_bounds__(256) void attn_merge(
    const unsigned short* __restrict__ oU, const unsigned short* __restrict__ oM,
    const float* __restrict__ stats, unsigned short* __restrict__ atb,
    const int* __restrict__ wsp) {
  const int tid = blockIdx.x * 256 + threadIdx.x;   // 524288 total
  const int d8 = tid & 15;
  const int q = (tid >> 4) & 2047;
  const int h = tid >> 15;
  const int qt = q >> 6, qloc = q & 63;
  const int b0 = (h * 2 + 0) * 32 + qt;
  const int b1 = (h * 2 + 1) * 32 + qt;

  const float mU0 = stats[b0 * 64 + qloc], mU1 = stats[b1 * 64 + qloc];
  const float lU0 = stats[65536 + b0 * 64 + qloc], lU1 = stats[65536 + b1 * 64 + qloc];
  const float mM0 = stats[131072 + b0 * 64 + qloc], mM1 = stats[131072 + b1 * 64 + qloc];
  const float lM0 = stats[196608 + b0 * 64 + qloc], lM1 = stats[196608 + b1 * 64 + qloc];

  const float m2 = fmaxf(mU0, mU1);
  const float e0 = exp2f(mU0 - m2), e1 = exp2f(mU1 - m2);
  const float l2 = lU0 * e0 + lU1 * e1;
  const float m1 = fmaxf(mM0, mM1);
  const float g0 = exp2f(mM0 - m1), g1 = exp2f(mM1 - m1);
  const float l1 = lM0 * g0 + lM1 * g1;

  const float fws = (float)(wsp[0] - 1);
  const float a = exp2f(m1 - m2);
  const float se = l1 * a + fws * l2;
  const float inv = 1.0f / (se + 1e-8f);
  const float f1 = (a / (l1 + 1e-8f)) * inv;
  const float f2 = (fws / (l2 + 1e-8f)) * inv;

  const size_t i0 = ((size_t)b0 * 64 + qloc) * 128 + d8 * 8;
  const size_t i1 = ((size_t)b1 * 64 + qloc) * 128 + d8 * 8;
  const ushort4* pU0 = (const ushort4*)(oU + i0);
  const ushort4* pU1 = (const ushort4*)(oU + i1);
  const ushort4* pM0 = (const ushort4*)(oM + i0);
  const ushort4* pM1 = (const ushort4*)(oM + i1);

  union { unsigned short u[8]; ushort4 v[2]; } out;
#pragma unroll
  for (int half = 0; half < 2; half++) {
    const ushort4 u0 = pU0[half], u1 = pU1[half], w0 = pM0[half], w1 = pM1[half];
    const unsigned short* a0 = (const unsigned short*)&u0;
    const unsigned short* a1 = (const unsigned short*)&u1;
    const unsigned short* c0 = (const unsigned short*)&w0;
    const unsigned short* c1 = (const unsigned short*)&w1;
#pragma unroll
    for (int k = 0; k < 4; k++) {
      const float ov2 = bf2f(a0[k]) * e0 + bf2f(a1[k]) * e1;
      const float ov1 = bf2f(c0[k]) * g0 + bf2f(c1[k]) * g1;
      out.u[half * 4 + k] = f2bf(ov1 * f1 + ov2 * f2);
    }
  }
  ushort4* dst = (ushort4*)(atb + (size_t)q * 2048 + h * 128 + d8 * 8);
  dst[0] = out.v[0];
  dst[1] = out.v[1];
}

// ------------------------------ O-proj GEMM --------------------------------
// out[2048 x 2048] fp32 = attn[2048 x 2048]bf16 * ow[2048 x 2048]^T + ob
// 64x128 tile, BK=128 (16 iters), chunk-XOR swizzle on 16-chunk rows.
__global__ __launch_bounds__(256) void gemm_o(
    const unsigned short* __restrict__ A, const unsigned short* __restrict__ Bt,
    const float* __restrict__ ob, float* __restrict__ Cout) {
  __shared__ __align__(16) unsigned short sA[64 * 128];
  __shared__ __align__(16) unsigned short sB[128 * 128];
  const int tid = threadIdx.x;
  const int wave = tid >> 6, lane = tid & 63;
  const int quad = lane >> 4, l16 = lane & 15;
  const int wm = wave >> 1, wn = wave & 1;
  const int m0 = blockIdx.y << 6, n0 = blockIdx.x << 7;

  f32x4 acc[2][4] = {};

  for (int k0 = 0; k0 < 2048; k0 += 128) {
    __syncthreads();
    // A: 64 rows x 16 chunks = 16 instr (4/wave)
#pragma unroll
    for (int t = 0; t < 4; t++) {
      const int i = t * 4 + wave;
      const int idx = i * 64 + lane;
      const int row = idx >> 4;
      const int c = (idx & 15) ^ (row & 15);
      load16_lds(A + (size_t)(m0 + row) * 2048 + k0 + c * 8, &sA[i * 512]);
    }
    // B: 128 rows x 16 chunks = 32 instr (8/wave)
#pragma unroll
    for (int t = 0; t < 8; t++) {
      const int i = t * 4 + wave;
      const int idx = i * 64 + lane;
      const int row = idx >> 4;
      const int c = (idx & 15) ^ (row & 15);
      load16_lds(Bt + (size_t)(n0 + row) * 2048 + k0 + c * 8, &sB[i * 512]);
    }
    __syncthreads();
#pragma unroll
    for (int ks = 0; ks < 4; ks++) {
      const int cs = ((ks * 4 + quad) ^ l16) << 3;
      bf16x8 af[2], bfr[4];
#pragma unroll
      for (int i = 0; i < 2; i++)
        af[i] = *(const bf16x8*)&sA[(wm * 32 + i * 16 + l16) * 128 + cs];
#pragma unroll
      for (int i = 0; i < 4; i++)
        bfr[i] = *(const bf16x8*)&sB[(wn * 64 + i * 16 + l16) * 128 + cs];
#pragma unroll
      for (int mi = 0; mi < 2; mi++)
#pragma unroll
        for (int ni = 0; ni < 4; ni++)
          acc[mi][ni] = MFMA_BF16(af[mi], bfr[ni], acc[mi][ni]);
    }
  }

#pragma unroll
  for (int mi = 0; mi < 2; mi++) {
    const int row = m0 + wm * 32 + mi * 16 + quad * 4;
#pragma unroll
    for (int ni = 0; ni < 4; ni++) {
      const int col = n0 + wn * 64 + ni * 16 + l16;
#pragma unroll
      for (int r = 0; r < 4; r++) {
        Cout[(size_t)(row + r) * 2048 + col] = acc[mi][ni][r] + ob[col];
      }
    }
  }
}

// ------------------------------- launcher ----------------------------------
extern "C" void kernel_launch(void* const* d_in, const int* in_sizes, int n_in,
                              void* d_out, int out_size, void* d_ws, size_t ws_size,
                              hipStream_t stream) {
  (void)in_sizes; (void)n_in; (void)out_size; (void)ws_size;
  const float* hs = (const float*)d_in[0];
  const float* qw = (const float*)d_in[1];
  const float* qb = (const float*)d_in[2];
  const float* kw = (const float*)d_in[3];
  const float* kb = (const float*)d_in[4];
  const float* vw = (const float*)d_in[5];
  const float* vb = (const float*)d_in[6];
  const float* ow = (const float*)d_in[7];
  const float* ob = (const float*)d_in[8];
  const int* wsz = (const int*)d_in[9];

  char* w = (char*)d_ws;
  // phase 1 (cvt + gemm_qkv): [0, 33.5 MB) = hsb(8) + wqkv(24)
  unsigned short* hsb  = (unsigned short*)(w + 0);
  unsigned short* wqkv = (unsigned short*)(w + 8388608);
  // phase 2 (attn): same region reused for partials: oU(16.78) + oM(16.78)
  unsigned short* oU   = (unsigned short*)(w + 0);
  unsigned short* oM   = (unsigned short*)(w + 16777216);
  unsigned short* owb  = (unsigned short*)(w + 33554432);   //  8 MB
  unsigned short* Qb_  = (unsigned short*)(w + 41943040);   //  8 MB (H,S,D)
  unsigned short* Kb_  = (unsigned short*)(w + 50331648);   //  8 MB (H,S,D)
  unsigned short* Vtb  = (unsigned short*)(w + 58720256);   //  8 MB (H,D,S)
  unsigned short* atb  = (unsigned short*)(w + 67108864);   //  8 MB (S,H*D)
  float*          stp  = (float*)(w + 75497472);            //  1 MB stats

  cvt_all<<<20480, 256, 0, stream>>>(
      (const float4*)hs, (const float4*)qw, (const float4*)kw, (const float4*)vw,
      (const float4*)ow,
      (ushort4*)hsb, (ushort4*)wqkv, (ushort4*)(wqkv + 4194304),
      (ushort4*)(wqkv + 8388608), (ushort4*)owb);

  gemm_qkv<<<dim3(48, 16), 256, 0, stream>>>(hsb, wqkv, qb, kb, vb, Qb_, Kb_, Vtb);
  attn_fwd<<<dim3(32, 2, 16), 128, 0, stream>>>(Qb_, Kb_, Vtb, oU, oM, stp);
  attn_merge<<<2048, 256, 0, stream>>>(oU, oM, stp, atb, wsz);
  gemm_o<<<dim3(16, 32), 256, 0, stream>>>(atb, owb, ob, (float*)d_out);
}

// Round 5
// 375.036 us; speedup vs baseline: 1.1123x; 1.1123x over previous
//
#include <hip/hip_runtime.h>
#include <hip/hip_bf16.h>
#include <stdint.h>
#include <stddef.h>

// ---------------------------------------------------------------------------
// RingAttentionLayer on MI355X (gfx950)
// R5: attention = R4's 32q/wave shared-fragment structure WITHOUT the k-split
// and WITHOUT global partials (R4 post-mortem: partial round trip caused 546MB
// HBM traffic). 2 waves/block, 64q/block, full K sweep, in-register ring
// combine. LDS 40KB -> 4 blocks/CU, 8 waves/CU. GEMMs as R4.
// ---------------------------------------------------------------------------

typedef __attribute__((ext_vector_type(8))) short bf16x8;   // 8 bf16 = 4 VGPRs
typedef __attribute__((ext_vector_type(4))) float f32x4;

#define MFMA_BF16(a, b, c) __builtin_amdgcn_mfma_f32_16x16x32_bf16((a), (b), (c), 0, 0, 0)

__device__ __forceinline__ void load16_lds(const void* g, void* l) {
  __builtin_amdgcn_global_load_lds((const __attribute__((address_space(1))) void*)g,
                                   (__attribute__((address_space(3))) void*)l,
                                   16, 0, 0);
}

__device__ __forceinline__ unsigned short f2bf(float x) {
  union { __hip_bfloat16 b; unsigned short u; } cv;
  cv.b = __float2bfloat16(x);
  return cv.u;
}

// ------------------------------- convert -----------------------------------
__global__ __launch_bounds__(256) void cvt_all(
    const float4* __restrict__ s0, const float4* __restrict__ s1,
    const float4* __restrict__ s2, const float4* __restrict__ s3,
    const float4* __restrict__ s4,
    ushort4* __restrict__ d0, ushort4* __restrict__ d1,
    ushort4* __restrict__ d2, ushort4* __restrict__ d3,
    ushort4* __restrict__ d4) {
  const int seg = blockIdx.x >> 12;
  const int i = ((blockIdx.x & 4095) << 8) + threadIdx.x;
  const float4* s = seg == 0 ? s0 : seg == 1 ? s1 : seg == 2 ? s2 : seg == 3 ? s3 : s4;
  ushort4* d = seg == 0 ? d0 : seg == 1 ? d1 : seg == 2 ? d2 : seg == 3 ? d3 : d4;
  float4 v = s[i];
  ushort4 o;
  o.x = f2bf(v.x); o.y = f2bf(v.y); o.z = f2bf(v.z); o.w = f2bf(v.w);
  d[i] = o;
}

// --------------------------- fused QKV GEMM --------------------------------
// (unchanged: 128x128 tile, BK=64, chunk-XOR swizzle; Q pre-scaled by
// softmax_scale*log2e; scatter Q->(H,S,D), K->(H,S,D), V->(H,D,S))
__global__ __launch_bounds__(256) void gemm_qkv(
    const unsigned short* __restrict__ A, const unsigned short* __restrict__ Bt,
    const float* __restrict__ qb, const float* __restrict__ kb,
    const float* __restrict__ vb,
    unsigned short* __restrict__ Qo, unsigned short* __restrict__ Ko,
    unsigned short* __restrict__ Vt) {
  __shared__ __align__(16) unsigned short sA[128 * 64];
  __shared__ __align__(16) unsigned short sB[128 * 64];
  const int tid = threadIdx.x;
  const int wave = tid >> 6, lane = tid & 63;
  const int quad = lane >> 4, l16 = lane & 15;
  const int wr = wave >> 1, wc = wave & 1;
  const int m0 = blockIdx.y << 7, n0 = blockIdx.x << 7;

  f32x4 acc[4][4] = {};

  for (int k0 = 0; k0 < 2048; k0 += 64) {
    __syncthreads();
#pragma unroll
    for (int t = 0; t < 4; t++) {
      const int i = t * 4 + wave;
      const int idx = i * 64 + lane;
      const int row = idx >> 3;
      const int c = (idx & 7) ^ (row & 7);
      load16_lds(A + (size_t)(m0 + row) * 2048 + k0 + c * 8, &sA[i * 512]);
      load16_lds(Bt + (size_t)(n0 + row) * 2048 + k0 + c * 8, &sB[i * 512]);
    }
    __syncthreads();
#pragma unroll
    for (int ks = 0; ks < 2; ks++) {
      bf16x8 af[4], bfr[4];
#pragma unroll
      for (int i = 0; i < 4; i++) {
        const int cs = ((ks * 4 + quad) ^ (l16 & 7)) << 3;
        af[i] = *(const bf16x8*)&sA[(wr * 64 + i * 16 + l16) * 64 + cs];
        bfr[i] = *(const bf16x8*)&sB[(wc * 64 + i * 16 + l16) * 64 + cs];
      }
#pragma unroll
      for (int mi = 0; mi < 4; mi++)
#pragma unroll
        for (int ni = 0; ni < 4; ni++)
          acc[mi][ni] = MFMA_BF16(af[mi], bfr[ni], acc[mi][ni]);
    }
  }

  const float qscale = 0.088388347648318447f * 1.4426950408889634f;  // scale*log2e
#pragma unroll
  for (int mi = 0; mi < 4; mi++) {
    const int row = m0 + wr * 64 + mi * 16 + quad * 4;
#pragma unroll
    for (int ni = 0; ni < 4; ni++) {
      const int col = n0 + wc * 64 + ni * 16 + l16;
#pragma unroll
      for (int r = 0; r < 4; r++) {
        const float v = acc[mi][ni][r];
        const int rr = row + r;
        if (col < 2048) {
          const int hh = col >> 7, d = col & 127;
          Qo[((size_t)hh * 2048 + rr) * 128 + d] = f2bf((v + qb[col]) * qscale);
        } else if (col < 4096) {
          const int f = col - 2048;
          const int hh = f >> 7, d = f & 127;
          Ko[((size_t)hh * 2048 + rr) * 128 + d] = f2bf(v + kb[f]);
        } else {
          const int f = col - 4096;
          const int hh = f >> 7, d = f & 127;
          Vt[((size_t)hh * 128 + d) * 2048 + rr] = f2bf(v + vb[f]);  // (H,D,S)
        }
      }
    }
  }
}

// ------------------------------ attention ----------------------------------
// grid (32 qtiles, 16 heads), block = 128 threads (2 waves), 40KB LDS ->
// 4 blocks/CU. Each wave owns 32 q (2 subtiles of 16) sharing every K/V
// fragment read across subtiles. Full K sweep; dual accumulators
// (masked fork at diag tile kt==qt); in-register ring combine at the end.
__global__ __launch_bounds__(128, 2) void attn_fwd(
    const unsigned short* __restrict__ Q, const unsigned short* __restrict__ K,
    const unsigned short* __restrict__ V,   // (H, D, S) transposed
    unsigned short* __restrict__ O,         // (S, H*D) bf16
    const int* __restrict__ wsp) {
  const int qt = blockIdx.x, h = blockIdx.y;
  const int tid = threadIdx.x;
  const int wave = tid >> 6, lane = tid & 63;
  const int quad = lane >> 4, l16 = lane & 15;

  __shared__ __align__(16) unsigned short sQK[64 * 128];  // Q staged, then K (overlay)
  __shared__ __align__(16) unsigned short sV[128 * 64];
  __shared__ __align__(16) unsigned short sP[2 * 2 * 1024];

  const unsigned short* Qh = Q + (size_t)h * 2048 * 128;
  const unsigned short* Kh = K + (size_t)h * 2048 * 128;
  const unsigned short* Vh = V + (size_t)h * 128 * 2048;

  // stage Q tile [64][128], chunk swizzle blk ^ (row&15)
  for (int c = wave; c < 16; c += 2) {
    const int rowc = lane >> 4;
    const int row = c * 4 + rowc;
    const int blk = (lane & 15) ^ (row & 15);
    load16_lds(Qh + (size_t)(qt * 64 + row) * 128 + blk * 8, &sQK[c * 512]);
  }
  __syncthreads();

  bf16x8 qf[2][4];
#pragma unroll
  for (int s = 0; s < 2; s++)
#pragma unroll
    for (int ds = 0; ds < 4; ds++)
      qf[s][ds] = *(const bf16x8*)&sQK[(wave * 32 + s * 16 + l16) * 128 +
                                       (((ds * 4 + quad) ^ l16) << 3)];

  float m1[2] = {-3.0e38f, -3.0e38f}, l1[2] = {0.f, 0.f};
  float m2[2] = {-3.0e38f, -3.0e38f}, l2[2] = {0.f, 0.f};
  f32x4 o1[2][8], o2[2][8];
#pragma unroll
  for (int s = 0; s < 2; s++)
#pragma unroll
    for (int j = 0; j < 8; j++) {
      o1[s][j] = f32x4{0.f, 0.f, 0.f, 0.f};
      o2[s][j] = f32x4{0.f, 0.f, 0.f, 0.f};
    }

  auto softmax_update = [&](int sub, float& m, float& l, f32x4 (&o)[8],
                            const f32x4 (&stt)[4], bool masked, int k0) {
    const int qg = qt * 64 + wave * 32 + sub * 16 + l16;  // this lane's q column
    float t[4][4];
    float mx = -3.0e38f;
#pragma unroll
    for (int ni = 0; ni < 4; ni++)
#pragma unroll
      for (int r = 0; r < 4; r++) {
        float v = stt[ni][r];
        if (masked && (k0 + ni * 16 + quad * 4 + r > qg)) v = -3.0e38f;
        t[ni][r] = v;
        mx = fmaxf(mx, v);
      }
    mx = fmaxf(mx, __shfl_xor(mx, 16));
    mx = fmaxf(mx, __shfl_xor(mx, 32));
    const float mn = fmaxf(m, mx);
    const float al = exp2f(m - mn);
    unsigned short* sPw = &sP[(wave * 2 + sub) * 1024];
    float rs = 0.f;
#pragma unroll
    for (int ni = 0; ni < 4; ni++) {
      union { unsigned short u[4]; uint2 v; } pk;
#pragma unroll
      for (int r = 0; r < 4; r++) {
        const float p = exp2f(t[ni][r] - mn);
        rs += p;
        pk.u[r] = f2bf(p);
      }
      const int off =
          l16 * 64 + (((ni * 2 + (quad >> 1)) ^ (l16 & 7)) << 3) + ((quad & 1) << 2);
      *(uint2*)&sPw[off] = pk.v;
    }
    rs += __shfl_xor(rs, 16);
    rs += __shfl_xor(rs, 32);
    l = l * al + rs;
    m = mn;
#pragma unroll
    for (int r = 0; r < 4; r++) {
      const int src = (lane & 48) + quad * 4 + r;  // same quad, l16 = quad*4+r
      const float ab = __shfl(al, src);
#pragma unroll
      for (int j = 0; j < 8; j++) o[j][r] *= ab;
    }
  };

  auto pv_shared = [&](f32x4 (&oo)[2][8]) {
#pragma unroll
    for (int ks = 0; ks < 2; ks++) {
      const int cs = (((ks * 4 + quad) ^ (l16 & 7)) << 3);
      const bf16x8 pf0 = *(const bf16x8*)&sP[(wave * 2 + 0) * 1024 + l16 * 64 + cs];
      const bf16x8 pf1 = *(const bf16x8*)&sP[(wave * 2 + 1) * 1024 + l16 * 64 + cs];
#pragma unroll
      for (int j = 0; j < 8; j++) {
        const bf16x8 vf = *(const bf16x8*)&sV[(j * 16 + l16) * 64 + cs];
        oo[0][j] = MFMA_BF16(pf0, vf, oo[0][j]);
        oo[1][j] = MFMA_BF16(pf1, vf, oo[1][j]);
      }
    }
  };

  for (int kt = 0; kt < 32; kt++) {
    const int k0 = kt << 6;
    __syncthreads();
    for (int c = wave; c < 16; c += 2) {
      {  // K tile [64][128] into sQK
        const int rowc = lane >> 4;
        const int row = c * 4 + rowc;
        const int blk = (lane & 15) ^ (row & 15);
        load16_lds(Kh + (size_t)(k0 + row) * 128 + blk * 8, &sQK[c * 512]);
      }
      {  // V tile [128 d][64 k]
        const int rowc = lane >> 3;
        const int row = c * 8 + rowc;
        const int blk = (lane & 7) ^ (rowc & 7);
        load16_lds(Vh + (size_t)row * 2048 + k0 + blk * 8, &sV[c * 512]);
      }
    }
    __syncthreads();

    // transposed scores, K-frag shared across both q-subtiles
    f32x4 st[2][4];
#pragma unroll
    for (int s = 0; s < 2; s++)
#pragma unroll
      for (int ni = 0; ni < 4; ni++) st[s][ni] = f32x4{0.f, 0.f, 0.f, 0.f};
#pragma unroll
    for (int ds = 0; ds < 4; ds++) {
#pragma unroll
      for (int ni = 0; ni < 4; ni++) {
        const bf16x8 kf =
            *(const bf16x8*)&sQK[(ni * 16 + l16) * 128 + (((ds * 4 + quad) ^ l16) << 3)];
        st[0][ni] = MFMA_BF16(kf, qf[0][ds], st[0][ni]);
        st[1][ni] = MFMA_BF16(kf, qf[1][ds], st[1][ni]);
      }
    }

    if (kt == qt) {  // diagonal tile: fork masked stats, dual update
#pragma unroll
      for (int s = 0; s < 2; s++) {
        m1[s] = m2[s]; l1[s] = l2[s];
#pragma unroll
        for (int j = 0; j < 8; j++) o1[s][j] = o2[s][j];
      }
      softmax_update(0, m1[0], l1[0], o1[0], st[0], true, k0);
      softmax_update(1, m1[1], l1[1], o1[1], st[1], true, k0);
      pv_shared(o1);
    }
    softmax_update(0, m2[0], l2[0], o2[0], st[0], false, k0);
    softmax_update(1, m2[1], l2[1], o2[1], st[1], false, k0);
    pv_shared(o2);
  }

  // in-register ring combine: 1x masked + (ws-1)x unmasked (log2 domain)
  const float fws = (float)(wsp[0] - 1);
#pragma unroll
  for (int s = 0; s < 2; s++) {
    const float a = exp2f(m1[s] - m2[s]);
    const float se = l1[s] * a + fws * l2[s];
    const float inv = 1.0f / (se + 1e-8f);
    const float f1 = (a / (l1[s] + 1e-8f)) * inv;
    const float f2 = (fws / (l2[s] + 1e-8f)) * inv;
#pragma unroll
    for (int r = 0; r < 4; r++) {
      const int src = (lane & 48) + quad * 4 + r;  // same quad, l16 = quad*4+r
      const float f1b = __shfl(f1, src);
      const float f2b = __shfl(f2, src);
      const int row = qt * 64 + wave * 32 + s * 16 + quad * 4 + r;
#pragma unroll
      for (int j = 0; j < 8; j++) {
        const float ov = o1[s][j][r] * f1b + o2[s][j][r] * f2b;
        O[(size_t)row * 2048 + h * 128 + j * 16 + l16] = f2bf(ov);
      }
    }
  }
}

// ------------------------------ O-proj GEMM --------------------------------
// out[2048 x 2048] fp32 = attn[2048 x 2048]bf16 * ow[2048 x 2048]^T + ob
// 64x128 tile, BK=128 (16 iters), chunk-XOR swizzle on 16-chunk rows.
__global__ __launch_bounds__(256) void gemm_o(
    const unsigned short* __restrict__ A, const unsigned short* __restrict__ Bt,
    const float* __restrict__ ob, float* __restrict__ Cout) {
  __shared__ __align__(16) unsigned short sA[64 * 128];
  __shared__ __align__(16) unsigned short sB[128 * 128];
  const int tid = threadIdx.x;
  const int wave = tid >> 6, lane = tid & 63;
  const int quad = lane >> 4, l16 = lane & 15;
  const int wm = wave >> 1, wn = wave & 1;
  const int m0 = blockIdx.y << 6, n0 = blockIdx.x << 7;

  f32x4 acc[2][4] = {};

  for (int k0 = 0; k0 < 2048; k0 += 128) {
    __syncthreads();
#pragma unroll
    for (int t = 0; t < 4; t++) {
      const int i = t * 4 + wave;
      const int idx = i * 64 + lane;
      const int row = idx >> 4;
      const int c = (idx & 15) ^ (row & 15);
      load16_lds(A + (size_t)(m0 + row) * 2048 + k0 + c * 8, &sA[i * 512]);
    }
#pragma unroll
    for (int t = 0; t < 8; t++) {
      const int i = t * 4 + wave;
      const int idx = i * 64 + lane;
      const int row = idx >> 4;
      const int c = (idx & 15) ^ (row & 15);
      load16_lds(Bt + (size_t)(n0 + row) * 2048 + k0 + c * 8, &sB[i * 512]);
    }
    __syncthreads();
#pragma unroll
    for (int ks = 0; ks < 4; ks++) {
      const int cs = ((ks * 4 + quad) ^ l16) << 3;
      bf16x8 af[2], bfr[4];
#pragma unroll
      for (int i = 0; i < 2; i++)
        af[i] = *(const bf16x8*)&sA[(wm * 32 + i * 16 + l16) * 128 + cs];
#pragma unroll
      for (int i = 0; i < 4; i++)
        bfr[i] = *(const bf16x8*)&sB[(wn * 64 + i * 16 + l16) * 128 + cs];
#pragma unroll
      for (int mi = 0; mi < 2; mi++)
#pragma unroll
        for (int ni = 0; ni < 4; ni++)
          acc[mi][ni] = MFMA_BF16(af[mi], bfr[ni], acc[mi][ni]);
    }
  }

#pragma unroll
  for (int mi = 0; mi < 2; mi++) {
    const int row = m0 + wm * 32 + mi * 16 + quad * 4;
#pragma unroll
    for (int ni = 0; ni < 4; ni++) {
      const int col = n0 + wn * 64 + ni * 16 + l16;
#pragma unroll
      for (int r = 0; r < 4; r++) {
        Cout[(size_t)(row + r) * 2048 + col] = acc[mi][ni][r] + ob[col];
      }
    }
  }
}

// ------------------------------- launcher ----------------------------------
extern "C" void kernel_launch(void* const* d_in, const int* in_sizes, int n_in,
                              void* d_out, int out_size, void* d_ws, size_t ws_size,
                              hipStream_t stream) {
  (void)in_sizes; (void)n_in; (void)out_size; (void)ws_size;
  const float* hs = (const float*)d_in[0];
  const float* qw = (const float*)d_in[1];
  const float* qb = (const float*)d_in[2];
  const float* kw = (const float*)d_in[3];
  const float* kb = (const float*)d_in[4];
  const float* vw = (const float*)d_in[5];
  const float* vb = (const float*)d_in[6];
  const float* ow = (const float*)d_in[7];
  const float* ob = (const float*)d_in[8];
  const int* wsz = (const int*)d_in[9];

  char* w = (char*)d_ws;
  unsigned short* hsb  = (unsigned short*)(w + 0);          //  8 MB (S,HID) bf16
  unsigned short* wqkv = (unsigned short*)(w + 8388608);    // 24 MB (6144,2048) bf16
  unsigned short* owb  = (unsigned short*)(w + 33554432);   //  8 MB
  unsigned short* Qb_  = (unsigned short*)(w + 41943040);   //  8 MB (H,S,D)
  unsigned short* Kb_  = (unsigned short*)(w + 50331648);   //  8 MB (H,S,D)
  unsigned short* Vtb  = (unsigned short*)(w + 58720256);   //  8 MB (H,D,S)
  unsigned short* atb  = (unsigned short*)(w + 67108864);   //  8 MB (S,H*D)

  cvt_all<<<20480, 256, 0, stream>>>(
      (const float4*)hs, (const float4*)qw, (const float4*)kw, (const float4*)vw,
      (const float4*)ow,
      (ushort4*)hsb, (ushort4*)wqkv, (ushort4*)(wqkv + 4194304),
      (ushort4*)(wqkv + 8388608), (ushort4*)owb);

  gemm_qkv<<<dim3(48, 16), 256, 0, stream>>>(hsb, wqkv, qb, kb, vb, Qb_, Kb_, Vtb);
  attn_fwd<<<dim3(32, 16), 128, 0, stream>>>(Qb_, Kb_, Vtb, atb, wsz);
  gemm_o<<<dim3(16, 32), 256, 0, stream>>>(atb, owb, ob, (float*)d_out);
}

// Round 6
// 347.233 us; speedup vs baseline: 1.2014x; 1.0801x over previous
//
#include <hip/hip_runtime.h>
#include <hip/hip_bf16.h>
#include <stdint.h>
#include <stddef.h>

// ---------------------------------------------------------------------------
// RingAttentionLayer on MI355X (gfx950)
// R6: attention gets explicit K/V LDS double-buffering (stage tile k+1 issued
// right after the barrier, full tile-k compute hides the load latency; the
// compiler's per-wave vmcnt(0)-before-barrier is the sync). 72KB LDS,
// 2 blocks/CU, 4 waves/CU (q-parallelism cap). Wave-uniform alpha-skip in
// online softmax. GEMMs/cvt unchanged from R5.
// ---------------------------------------------------------------------------

typedef __attribute__((ext_vector_type(8))) short bf16x8;   // 8 bf16 = 4 VGPRs
typedef __attribute__((ext_vector_type(4))) float f32x4;

#define MFMA_BF16(a, b, c) __builtin_amdgcn_mfma_f32_16x16x32_bf16((a), (b), (c), 0, 0, 0)

__device__ __forceinline__ void load16_lds(const void* g, void* l) {
  __builtin_amdgcn_global_load_lds((const __attribute__((address_space(1))) void*)g,
                                   (__attribute__((address_space(3))) void*)l,
                                   16, 0, 0);
}

__device__ __forceinline__ unsigned short f2bf(float x) {
  union { __hip_bfloat16 b; unsigned short u; } cv;
  cv.b = __float2bfloat16(x);
  return cv.u;
}

// ------------------------------- convert -----------------------------------
__global__ __launch_bounds__(256) void cvt_all(
    const float4* __restrict__ s0, const float4* __restrict__ s1,
    const float4* __restrict__ s2, const float4* __restrict__ s3,
    const float4* __restrict__ s4,
    ushort4* __restrict__ d0, ushort4* __restrict__ d1,
    ushort4* __restrict__ d2, ushort4* __restrict__ d3,
    ushort4* __restrict__ d4) {
  const int seg = blockIdx.x >> 12;
  const int i = ((blockIdx.x & 4095) << 8) + threadIdx.x;
  const float4* s = seg == 0 ? s0 : seg == 1 ? s1 : seg == 2 ? s2 : seg == 3 ? s3 : s4;
  ushort4* d = seg == 0 ? d0 : seg == 1 ? d1 : seg == 2 ? d2 : seg == 3 ? d3 : d4;
  float4 v = s[i];
  ushort4 o;
  o.x = f2bf(v.x); o.y = f2bf(v.y); o.z = f2bf(v.z); o.w = f2bf(v.w);
  d[i] = o;
}

// --------------------------- fused QKV GEMM --------------------------------
// (unchanged: 128x128 tile, BK=64, chunk-XOR swizzle; Q pre-scaled by
// softmax_scale*log2e; scatter Q->(H,S,D), K->(H,S,D), V->(H,D,S))
__global__ __launch_bounds__(256) void gemm_qkv(
    const unsigned short* __restrict__ A, const unsigned short* __restrict__ Bt,
    const float* __restrict__ qb, const float* __restrict__ kb,
    const float* __restrict__ vb,
    unsigned short* __restrict__ Qo, unsigned short* __restrict__ Ko,
    unsigned short* __restrict__ Vt) {
  __shared__ __align__(16) unsigned short sA[128 * 64];
  __shared__ __align__(16) unsigned short sB[128 * 64];
  const int tid = threadIdx.x;
  const int wave = tid >> 6, lane = tid & 63;
  const int quad = lane >> 4, l16 = lane & 15;
  const int wr = wave >> 1, wc = wave & 1;
  const int m0 = blockIdx.y << 7, n0 = blockIdx.x << 7;

  f32x4 acc[4][4] = {};

  for (int k0 = 0; k0 < 2048; k0 += 64) {
    __syncthreads();
#pragma unroll
    for (int t = 0; t < 4; t++) {
      const int i = t * 4 + wave;
      const int idx = i * 64 + lane;
      const int row = idx >> 3;
      const int c = (idx & 7) ^ (row & 7);
      load16_lds(A + (size_t)(m0 + row) * 2048 + k0 + c * 8, &sA[i * 512]);
      load16_lds(Bt + (size_t)(n0 + row) * 2048 + k0 + c * 8, &sB[i * 512]);
    }
    __syncthreads();
#pragma unroll
    for (int ks = 0; ks < 2; ks++) {
      bf16x8 af[4], bfr[4];
#pragma unroll
      for (int i = 0; i < 4; i++) {
        const int cs = ((ks * 4 + quad) ^ (l16 & 7)) << 3;
        af[i] = *(const bf16x8*)&sA[(wr * 64 + i * 16 + l16) * 64 + cs];
        bfr[i] = *(const bf16x8*)&sB[(wc * 64 + i * 16 + l16) * 64 + cs];
      }
#pragma unroll
      for (int mi = 0; mi < 4; mi++)
#pragma unroll
        for (int ni = 0; ni < 4; ni++)
          acc[mi][ni] = MFMA_BF16(af[mi], bfr[ni], acc[mi][ni]);
    }
  }

  const float qscale = 0.088388347648318447f * 1.4426950408889634f;  // scale*log2e
#pragma unroll
  for (int mi = 0; mi < 4; mi++) {
    const int row = m0 + wr * 64 + mi * 16 + quad * 4;
#pragma unroll
    for (int ni = 0; ni < 4; ni++) {
      const int col = n0 + wc * 64 + ni * 16 + l16;
#pragma unroll
      for (int r = 0; r < 4; r++) {
        const float v = acc[mi][ni][r];
        const int rr = row + r;
        if (col < 2048) {
          const int hh = col >> 7, d = col & 127;
          Qo[((size_t)hh * 2048 + rr) * 128 + d] = f2bf((v + qb[col]) * qscale);
        } else if (col < 4096) {
          const int f = col - 2048;
          const int hh = f >> 7, d = f & 127;
          Ko[((size_t)hh * 2048 + rr) * 128 + d] = f2bf(v + kb[f]);
        } else {
          const int f = col - 4096;
          const int hh = f >> 7, d = f & 127;
          Vt[((size_t)hh * 128 + d) * 2048 + rr] = f2bf(v + vb[f]);  // (H,D,S)
        }
      }
    }
  }
}

// ------------------------------ attention ----------------------------------
// grid (32 qtiles, 16 heads), block = 128 threads (2 waves), 72KB LDS ->
// 2 blocks/CU. K/V double-buffered: stage(kt+1) issued right after the
// barrier, tile-kt compute hides it; the per-wave vmcnt(0)+barrier is the
// buffer handoff. Dual accumulators (masked fork at kt==qt); in-register
// ring combine.
__global__ __launch_bounds__(128, 1) void attn_fwd(
    const unsigned short* __restrict__ Q, const unsigned short* __restrict__ K,
    const unsigned short* __restrict__ V,   // (H, D, S) transposed
    unsigned short* __restrict__ O,         // (S, H*D) bf16
    const int* __restrict__ wsp) {
  const int qt = blockIdx.x, h = blockIdx.y;
  const int tid = threadIdx.x;
  const int wave = tid >> 6, lane = tid & 63;
  const int quad = lane >> 4, l16 = lane & 15;

  __shared__ __align__(16) unsigned short sK0[64 * 128];  // Q staged here first
  __shared__ __align__(16) unsigned short sK1[64 * 128];
  __shared__ __align__(16) unsigned short sV0[128 * 64];
  __shared__ __align__(16) unsigned short sV1[128 * 64];
  __shared__ __align__(16) unsigned short sP[2 * 2 * 1024];

  const unsigned short* Qh = Q + (size_t)h * 2048 * 128;
  const unsigned short* Kh = K + (size_t)h * 2048 * 128;
  const unsigned short* Vh = V + (size_t)h * 128 * 2048;

  // stage Q tile [64][128] into sK0, chunk swizzle blk ^ (row&15)
  for (int c = wave; c < 16; c += 2) {
    const int rowc = lane >> 4;
    const int row = c * 4 + rowc;
    const int blk = (lane & 15) ^ (row & 15);
    load16_lds(Qh + (size_t)(qt * 64 + row) * 128 + blk * 8, &sK0[c * 512]);
  }
  __syncthreads();

  bf16x8 qf[2][4];
#pragma unroll
  for (int s = 0; s < 2; s++)
#pragma unroll
    for (int ds = 0; ds < 4; ds++)
      qf[s][ds] = *(const bf16x8*)&sK0[(wave * 32 + s * 16 + l16) * 128 +
                                       (((ds * 4 + quad) ^ l16) << 3)];
  __syncthreads();  // all waves hold Q frags before K0 overwrites sK0

  float m1[2] = {-3.0e38f, -3.0e38f}, l1[2] = {0.f, 0.f};
  float m2[2] = {-3.0e38f, -3.0e38f}, l2[2] = {0.f, 0.f};
  f32x4 o1[2][8], o2[2][8];
#pragma unroll
  for (int s = 0; s < 2; s++)
#pragma unroll
    for (int j = 0; j < 8; j++) {
      o1[s][j] = f32x4{0.f, 0.f, 0.f, 0.f};
      o2[s][j] = f32x4{0.f, 0.f, 0.f, 0.f};
    }

  auto stageKV = [&](int kt, unsigned short* kDst, unsigned short* vDst) {
    const int k0 = kt << 6;
    for (int c = wave; c < 16; c += 2) {
      {  // K tile [64 k][128 d]
        const int rowc = lane >> 4;
        const int row = c * 4 + rowc;
        const int blk = (lane & 15) ^ (row & 15);
        load16_lds(Kh + (size_t)(k0 + row) * 128 + blk * 8, &kDst[c * 512]);
      }
      {  // V tile [128 d][64 k]
        const int rowc = lane >> 3;
        const int row = c * 8 + rowc;
        const int blk = (lane & 7) ^ (rowc & 7);
        load16_lds(Vh + (size_t)row * 2048 + k0 + blk * 8, &vDst[c * 512]);
      }
    }
  };

  auto softmax_update = [&](int sub, float& m, float& l, f32x4 (&o)[8],
                            const f32x4 (&stt)[4], bool masked, int k0) {
    const int qg = qt * 64 + wave * 32 + sub * 16 + l16;  // this lane's q column
    float t[4][4];
    float mx = -3.0e38f;
#pragma unroll
    for (int ni = 0; ni < 4; ni++)
#pragma unroll
      for (int r = 0; r < 4; r++) {
        float v = stt[ni][r];
        if (masked && (k0 + ni * 16 + quad * 4 + r > qg)) v = -3.0e38f;
        t[ni][r] = v;
        mx = fmaxf(mx, v);
      }
    mx = fmaxf(mx, __shfl_xor(mx, 16));
    mx = fmaxf(mx, __shfl_xor(mx, 32));
    const float mn = fmaxf(m, mx);
    const float al = exp2f(m - mn);
    unsigned short* sPw = &sP[(wave * 2 + sub) * 1024];
    float rs = 0.f;
#pragma unroll
    for (int ni = 0; ni < 4; ni++) {
      union { unsigned short u[4]; uint2 v; } pk;
#pragma unroll
      for (int r = 0; r < 4; r++) {
        const float p = exp2f(t[ni][r] - mn);
        rs += p;
        pk.u[r] = f2bf(p);
      }
      const int off =
          l16 * 64 + (((ni * 2 + (quad >> 1)) ^ (l16 & 7)) << 3) + ((quad & 1) << 2);
      *(uint2*)&sPw[off] = pk.v;
    }
    rs += __shfl_xor(rs, 16);
    rs += __shfl_xor(rs, 32);
    const bool grew = !__all(mn == m);
    l = l * al + rs;
    m = mn;
    if (grew) {  // wave-uniform: skip o-rescale when no lane's max moved
#pragma unroll
      for (int r = 0; r < 4; r++) {
        const int src = (lane & 48) + quad * 4 + r;  // same quad, l16 = quad*4+r
        const float ab = __shfl(al, src);
#pragma unroll
        for (int j = 0; j < 8; j++) o[j][r] *= ab;
      }
    }
  };

  auto pv_shared = [&](f32x4 (&oo)[2][8], const unsigned short* vBuf) {
#pragma unroll
    for (int ks = 0; ks < 2; ks++) {
      const int cs = (((ks * 4 + quad) ^ (l16 & 7)) << 3);
      const bf16x8 pf0 = *(const bf16x8*)&sP[(wave * 2 + 0) * 1024 + l16 * 64 + cs];
      const bf16x8 pf1 = *(const bf16x8*)&sP[(wave * 2 + 1) * 1024 + l16 * 64 + cs];
#pragma unroll
      for (int j = 0; j < 8; j++) {
        const bf16x8 vf = *(const bf16x8*)&vBuf[(j * 16 + l16) * 64 + cs];
        oo[0][j] = MFMA_BF16(pf0, vf, oo[0][j]);
        oo[1][j] = MFMA_BF16(pf1, vf, oo[1][j]);
      }
    }
  };

  auto compute_tile = [&](int kt, const unsigned short* kBuf,
                          const unsigned short* vBuf) {
    const int k0 = kt << 6;
    f32x4 st[2][4];
#pragma unroll
    for (int s = 0; s < 2; s++)
#pragma unroll
      for (int ni = 0; ni < 4; ni++) st[s][ni] = f32x4{0.f, 0.f, 0.f, 0.f};
#pragma unroll
    for (int ds = 0; ds < 4; ds++) {
#pragma unroll
      for (int ni = 0; ni < 4; ni++) {
        const bf16x8 kf =
            *(const bf16x8*)&kBuf[(ni * 16 + l16) * 128 + (((ds * 4 + quad) ^ l16) << 3)];
        st[0][ni] = MFMA_BF16(kf, qf[0][ds], st[0][ni]);
        st[1][ni] = MFMA_BF16(kf, qf[1][ds], st[1][ni]);
      }
    }

    if (kt == qt) {  // diagonal: fork masked stats, dual update
#pragma unroll
      for (int s = 0; s < 2; s++) {
        m1[s] = m2[s]; l1[s] = l2[s];
#pragma unroll
        for (int j = 0; j < 8; j++) o1[s][j] = o2[s][j];
      }
      softmax_update(0, m1[0], l1[0], o1[0], st[0], true, k0);
      softmax_update(1, m1[1], l1[1], o1[1], st[1], true, k0);
      pv_shared(o1, vBuf);
    }
    softmax_update(0, m2[0], l2[0], o2[0], st[0], false, k0);
    softmax_update(1, m2[1], l2[1], o2[1], st[1], false, k0);
    pv_shared(o2, vBuf);
  };

  // pipelined K-loop: stage(kt+1) issues right after the barrier that
  // drained stage(kt); compute(kt) hides the latency.
  stageKV(0, sK0, sV0);
  for (int kt2 = 0; kt2 < 32; kt2 += 2) {
    __syncthreads();                       // drains stage(kt2) [buf0]
    if (kt2 + 1 < 32) stageKV(kt2 + 1, sK1, sV1);
    compute_tile(kt2, sK0, sV0);
    __syncthreads();                       // drains stage(kt2+1) [buf1]
    if (kt2 + 2 < 32) stageKV(kt2 + 2, sK0, sV0);
    compute_tile(kt2 + 1, sK1, sV1);
  }

  // in-register ring combine: 1x masked + (ws-1)x unmasked (log2 domain)
  const float fws = (float)(wsp[0] - 1);
#pragma unroll
  for (int s = 0; s < 2; s++) {
    const float a = exp2f(m1[s] - m2[s]);
    const float se = l1[s] * a + fws * l2[s];
    const float inv = 1.0f / (se + 1e-8f);
    const float f1 = (a / (l1[s] + 1e-8f)) * inv;
    const float f2 = (fws / (l2[s] + 1e-8f)) * inv;
#pragma unroll
    for (int r = 0; r < 4; r++) {
      const int src = (lane & 48) + quad * 4 + r;  // same quad, l16 = quad*4+r
      const float f1b = __shfl(f1, src);
      const float f2b = __shfl(f2, src);
      const int row = qt * 64 + wave * 32 + s * 16 + quad * 4 + r;
#pragma unroll
      for (int j = 0; j < 8; j++) {
        const float ov = o1[s][j][r] * f1b + o2[s][j][r] * f2b;
        O[(size_t)row * 2048 + h * 128 + j * 16 + l16] = f2bf(ov);
      }
    }
  }
}

// ------------------------------ O-proj GEMM --------------------------------
// out[2048 x 2048] fp32 = attn[2048 x 2048]bf16 * ow[2048 x 2048]^T + ob
// 64x128 tile, BK=128 (16 iters), chunk-XOR swizzle on 16-chunk rows.
__global__ __launch_bounds__(256) void gemm_o(
    const unsigned short* __restrict__ A, const unsigned short* __restrict__ Bt,
    const float* __restrict__ ob, float* __restrict__ Cout) {
  __shared__ __align__(16) unsigned short sA[64 * 128];
  __shared__ __align__(16) unsigned short sB[128 * 128];
  const int tid = threadIdx.x;
  const int wave = tid >> 6, lane = tid & 63;
  const int quad = lane >> 4, l16 = lane & 15;
  const int wm = wave >> 1, wn = wave & 1;
  const int m0 = blockIdx.y << 6, n0 = blockIdx.x << 7;

  f32x4 acc[2][4] = {};

  for (int k0 = 0; k0 < 2048; k0 += 128) {
    __syncthreads();
#pragma unroll
    for (int t = 0; t < 4; t++) {
      const int i = t * 4 + wave;
      const int idx = i * 64 + lane;
      const int row = idx >> 4;
      const int c = (idx & 15) ^ (row & 15);
      load16_lds(A + (size_t)(m0 + row) * 2048 + k0 + c * 8, &sA[i * 512]);
    }
#pragma unroll
    for (int t = 0; t < 8; t++) {
      const int i = t * 4 + wave;
      const int idx = i * 64 + lane;
      const int row = idx >> 4;
      const int c = (idx & 15) ^ (row & 15);
      load16_lds(Bt + (size_t)(n0 + row) * 2048 + k0 + c * 8, &sB[i * 512]);
    }
    __syncthreads();
#pragma unroll
    for (int ks = 0; ks < 4; ks++) {
      const int cs = ((ks * 4 + quad) ^ l16) << 3;
      bf16x8 af[2], bfr[4];
#pragma unroll
      for (int i = 0; i < 2; i++)
        af[i] = *(const bf16x8*)&sA[(wm * 32 + i * 16 + l16) * 128 + cs];
#pragma unroll
      for (int i = 0; i < 4; i++)
        bfr[i] = *(const bf16x8*)&sB[(wn * 64 + i * 16 + l16) * 128 + cs];
#pragma unroll
      for (int mi = 0; mi < 2; mi++)
#pragma unroll
        for (int ni = 0; ni < 4; ni++)
          acc[mi][ni] = MFMA_BF16(af[mi], bfr[ni], acc[mi][ni]);
    }
  }

#pragma unroll
  for (int mi = 0; mi < 2; mi++) {
    const int row = m0 + wm * 32 + mi * 16 + quad * 4;
#pragma unroll
    for (int ni = 0; ni < 4; ni++) {
      const int col = n0 + wn * 64 + ni * 16 + l16;
#pragma unroll
      for (int r = 0; r < 4; r++) {
        Cout[(size_t)(row + r) * 2048 + col] = acc[mi][ni][r] + ob[col];
      }
    }
  }
}

// ------------------------------- launcher ----------------------------------
extern "C" void kernel_launch(void* const* d_in, const int* in_sizes, int n_in,
                              void* d_out, int out_size, void* d_ws, size_t ws_size,
                              hipStream_t stream) {
  (void)in_sizes; (void)n_in; (void)out_size; (void)ws_size;
  const float* hs = (const float*)d_in[0];
  const float* qw = (const float*)d_in[1];
  const float* qb = (const float*)d_in[2];
  const float* kw = (const float*)d_in[3];
  const float* kb = (const float*)d_in[4];
  const float* vw = (const float*)d_in[5];
  const float* vb = (const float*)d_in[6];
  const float* ow = (const float*)d_in[7];
  const float* ob = (const float*)d_in[8];
  const int* wsz = (const int*)d_in[9];

  char* w = (char*)d_ws;
  unsigned short* hsb  = (unsigned short*)(w + 0);          //  8 MB (S,HID) bf16
  unsigned short* wqkv = (unsigned short*)(w + 8388608);    // 24 MB (6144,2048) bf16
  unsigned short* owb  = (unsigned short*)(w + 33554432);   //  8 MB
  unsigned short* Qb_  = (unsigned short*)(w + 41943040);   //  8 MB (H,S,D)
  unsigned short* Kb_  = (unsigned short*)(w + 50331648);   //  8 MB (H,S,D)
  unsigned short* Vtb  = (unsigned short*)(w + 58720256);   //  8 MB (H,D,S)
  unsigned short* atb  = (unsigned short*)(w + 67108864);   //  8 MB (S,H*D)

  cvt_all<<<20480, 256, 0, stream>>>(
      (const float4*)hs, (const float4*)qw, (const float4*)kw, (const float4*)vw,
      (const float4*)ow,
      (ushort4*)hsb, (ushort4*)wqkv, (ushort4*)(wqkv + 4194304),
      (ushort4*)(wqkv + 8388608), (ushort4*)owb);

  gemm_qkv<<<dim3(48, 16), 256, 0, stream>>>(hsb, wqkv, qb, kb, vb, Qb_, Kb_, Vtb);
  attn_fwd<<<dim3(32, 16), 128, 0, stream>>>(Qb_, Kb_, Vtb, atb, wsz);
  gemm_o<<<dim3(16, 32), 256, 0, stream>>>(atb, owb, ob, (float*)d_out);
}

// Round 7
// 322.366 us; speedup vs baseline: 1.2940x; 1.0771x over previous
//
#include <hip/hip_runtime.h>
#include <hip/hip_bf16.h>
#include <stdint.h>
#include <stddef.h>

// ---------------------------------------------------------------------------
// RingAttentionLayer on MI355X (gfx950)
// R7: attention = R3's 16q/wave 4-wave blocks (8 waves/CU = 2/SIMD, cross-wave
// latency hiding) + R6's K/V LDS double-buffer + alpha-skip. 72KB LDS,
// 2 blocks/CU co-resident (grid 512 = exactly 2/CU). GEMMs/cvt = R6.
// R6 lesson: 2-wave blocks gave 1 wave/SIMD -> zero cross-wave overlap; the
// serial QK->softmax->PV chain was fully latency-exposed.
// ---------------------------------------------------------------------------

typedef __attribute__((ext_vector_type(8))) short bf16x8;   // 8 bf16 = 4 VGPRs
typedef __attribute__((ext_vector_type(4))) float f32x4;

#define MFMA_BF16(a, b, c) __builtin_amdgcn_mfma_f32_16x16x32_bf16((a), (b), (c), 0, 0, 0)

__device__ __forceinline__ void load16_lds(const void* g, void* l) {
  __builtin_amdgcn_global_load_lds((const __attribute__((address_space(1))) void*)g,
                                   (__attribute__((address_space(3))) void*)l,
                                   16, 0, 0);
}

__device__ __forceinline__ unsigned short f2bf(float x) {
  union { __hip_bfloat16 b; unsigned short u; } cv;
  cv.b = __float2bfloat16(x);
  return cv.u;
}

// ------------------------------- convert -----------------------------------
__global__ __launch_bounds__(256) void cvt_all(
    const float4* __restrict__ s0, const float4* __restrict__ s1,
    const float4* __restrict__ s2, const float4* __restrict__ s3,
    const float4* __restrict__ s4,
    ushort4* __restrict__ d0, ushort4* __restrict__ d1,
    ushort4* __restrict__ d2, ushort4* __restrict__ d3,
    ushort4* __restrict__ d4) {
  const int seg = blockIdx.x >> 12;
  const int i = ((blockIdx.x & 4095) << 8) + threadIdx.x;
  const float4* s = seg == 0 ? s0 : seg == 1 ? s1 : seg == 2 ? s2 : seg == 3 ? s3 : s4;
  ushort4* d = seg == 0 ? d0 : seg == 1 ? d1 : seg == 2 ? d2 : seg == 3 ? d3 : d4;
  float4 v = s[i];
  ushort4 o;
  o.x = f2bf(v.x); o.y = f2bf(v.y); o.z = f2bf(v.z); o.w = f2bf(v.w);
  d[i] = o;
}

// --------------------------- fused QKV GEMM --------------------------------
// (unchanged: 128x128 tile, BK=64, chunk-XOR swizzle; Q pre-scaled by
// softmax_scale*log2e; scatter Q->(H,S,D), K->(H,S,D), V->(H,D,S))
__global__ __launch_bounds__(256) void gemm_qkv(
    const unsigned short* __restrict__ A, const unsigned short* __restrict__ Bt,
    const float* __restrict__ qb, const float* __restrict__ kb,
    const float* __restrict__ vb,
    unsigned short* __restrict__ Qo, unsigned short* __restrict__ Ko,
    unsigned short* __restrict__ Vt) {
  __shared__ __align__(16) unsigned short sA[128 * 64];
  __shared__ __align__(16) unsigned short sB[128 * 64];
  const int tid = threadIdx.x;
  const int wave = tid >> 6, lane = tid & 63;
  const int quad = lane >> 4, l16 = lane & 15;
  const int wr = wave >> 1, wc = wave & 1;
  const int m0 = blockIdx.y << 7, n0 = blockIdx.x << 7;

  f32x4 acc[4][4] = {};

  for (int k0 = 0; k0 < 2048; k0 += 64) {
    __syncthreads();
#pragma unroll
    for (int t = 0; t < 4; t++) {
      const int i = t * 4 + wave;
      const int idx = i * 64 + lane;
      const int row = idx >> 3;
      const int c = (idx & 7) ^ (row & 7);
      load16_lds(A + (size_t)(m0 + row) * 2048 + k0 + c * 8, &sA[i * 512]);
      load16_lds(Bt + (size_t)(n0 + row) * 2048 + k0 + c * 8, &sB[i * 512]);
    }
    __syncthreads();
#pragma unroll
    for (int ks = 0; ks < 2; ks++) {
      bf16x8 af[4], bfr[4];
#pragma unroll
      for (int i = 0; i < 4; i++) {
        const int cs = ((ks * 4 + quad) ^ (l16 & 7)) << 3;
        af[i] = *(const bf16x8*)&sA[(wr * 64 + i * 16 + l16) * 64 + cs];
        bfr[i] = *(const bf16x8*)&sB[(wc * 64 + i * 16 + l16) * 64 + cs];
      }
#pragma unroll
      for (int mi = 0; mi < 4; mi++)
#pragma unroll
        for (int ni = 0; ni < 4; ni++)
          acc[mi][ni] = MFMA_BF16(af[mi], bfr[ni], acc[mi][ni]);
    }
  }

  const float qscale = 0.088388347648318447f * 1.4426950408889634f;  // scale*log2e
#pragma unroll
  for (int mi = 0; mi < 4; mi++) {
    const int row = m0 + wr * 64 + mi * 16 + quad * 4;
#pragma unroll
    for (int ni = 0; ni < 4; ni++) {
      const int col = n0 + wc * 64 + ni * 16 + l16;
#pragma unroll
      for (int r = 0; r < 4; r++) {
        const float v = acc[mi][ni][r];
        const int rr = row + r;
        if (col < 2048) {
          const int hh = col >> 7, d = col & 127;
          Qo[((size_t)hh * 2048 + rr) * 128 + d] = f2bf((v + qb[col]) * qscale);
        } else if (col < 4096) {
          const int f = col - 2048;
          const int hh = f >> 7, d = f & 127;
          Ko[((size_t)hh * 2048 + rr) * 128 + d] = f2bf(v + kb[f]);
        } else {
          const int f = col - 4096;
          const int hh = f >> 7, d = f & 127;
          Vt[((size_t)hh * 128 + d) * 2048 + rr] = f2bf(v + vb[f]);  // (H,D,S)
        }
      }
    }
  }
}

// ------------------------------ attention ----------------------------------
// grid (32 qtiles, 16 heads) = 512 blocks, block = 256 threads (4 waves),
// 72KB LDS -> exactly 2 blocks/CU = 8 waves/CU = 2 waves/SIMD. Each wave owns
// 16 q. K/V double-buffered (stage kt+1 after the barrier draining stage kt).
// Transposed-score softmax (lane-private + 2 shfl), dual accumulators with
// masked fork at kt==qt, in-register ring combine.
__global__ __launch_bounds__(256, 2) void attn_fwd(
    const unsigned short* __restrict__ Q, const unsigned short* __restrict__ K,
    const unsigned short* __restrict__ V,   // (H, D, S) transposed
    unsigned short* __restrict__ O,         // (S, H*D) bf16
    const int* __restrict__ wsp) {
  const int qt = blockIdx.x, h = blockIdx.y;
  const int tid = threadIdx.x;
  const int wave = tid >> 6, lane = tid & 63;
  const int quad = lane >> 4, l16 = lane & 15;

  __shared__ __align__(16) unsigned short sK0[64 * 128];  // Q staged here first
  __shared__ __align__(16) unsigned short sK1[64 * 128];
  __shared__ __align__(16) unsigned short sV0[128 * 64];
  __shared__ __align__(16) unsigned short sV1[128 * 64];
  __shared__ __align__(16) unsigned short sP[4][16 * 64];

  const unsigned short* Qh = Q + (size_t)h * 2048 * 128;
  const unsigned short* Kh = K + (size_t)h * 2048 * 128;
  const unsigned short* Vh = V + (size_t)h * 128 * 2048;
  unsigned short* sPw = sP[wave];

  // stage Q tile [64][128] into sK0, chunk swizzle blk ^ (row&15)
  for (int c = wave; c < 16; c += 4) {
    const int rowc = lane >> 4;
    const int row = c * 4 + rowc;
    const int blk = (lane & 15) ^ (row & 15);
    load16_lds(Qh + (size_t)(qt * 64 + row) * 128 + blk * 8, &sK0[c * 512]);
  }
  __syncthreads();

  bf16x8 qf[4];
#pragma unroll
  for (int ds = 0; ds < 4; ds++)
    qf[ds] = *(const bf16x8*)&sK0[(wave * 16 + l16) * 128 + (((ds * 4 + quad) ^ l16) << 3)];
  __syncthreads();  // all waves hold Q frags before K0 overwrites sK0

  float m1 = -3.0e38f, l1 = 0.f, m2 = -3.0e38f, l2 = 0.f;
  f32x4 o1[8], o2[8];
#pragma unroll
  for (int j = 0; j < 8; j++) { o1[j] = f32x4{0.f, 0.f, 0.f, 0.f}; o2[j] = f32x4{0.f, 0.f, 0.f, 0.f}; }

  auto stageKV = [&](int kt, unsigned short* kDst, unsigned short* vDst) {
    const int k0 = kt << 6;
    for (int c = wave; c < 16; c += 4) {
      {  // K tile [64 k][128 d]
        const int rowc = lane >> 4;
        const int row = c * 4 + rowc;
        const int blk = (lane & 15) ^ (row & 15);
        load16_lds(Kh + (size_t)(k0 + row) * 128 + blk * 8, &kDst[c * 512]);
      }
      {  // V tile [128 d][64 k]
        const int rowc = lane >> 3;
        const int row = c * 8 + rowc;
        const int blk = (lane & 7) ^ (rowc & 7);
        load16_lds(Vh + (size_t)row * 2048 + k0 + blk * 8, &vDst[c * 512]);
      }
    }
  };

  auto softmax_update = [&](float& m, float& l, f32x4 (&o)[8],
                            const f32x4 (&stt)[4], bool masked, int k0) {
    const int qg = qt * 64 + wave * 16 + l16;  // this lane's q column
    float t[4][4];
    float mx = -3.0e38f;
#pragma unroll
    for (int ni = 0; ni < 4; ni++)
#pragma unroll
      for (int r = 0; r < 4; r++) {
        float v = stt[ni][r];
        if (masked && (k0 + ni * 16 + quad * 4 + r > qg)) v = -3.0e38f;
        t[ni][r] = v;
        mx = fmaxf(mx, v);
      }
    mx = fmaxf(mx, __shfl_xor(mx, 16));
    mx = fmaxf(mx, __shfl_xor(mx, 32));
    const float mn = fmaxf(m, mx);
    const float al = exp2f(m - mn);
    float rs = 0.f;
#pragma unroll
    for (int ni = 0; ni < 4; ni++) {
      union { unsigned short u[4]; uint2 v; } pk;
#pragma unroll
      for (int r = 0; r < 4; r++) {
        const float p = exp2f(t[ni][r] - mn);
        rs += p;
        pk.u[r] = f2bf(p);
      }
      const int off =
          l16 * 64 + (((ni * 2 + (quad >> 1)) ^ (l16 & 7)) << 3) + ((quad & 1) << 2);
      *(uint2*)&sPw[off] = pk.v;
    }
    rs += __shfl_xor(rs, 16);
    rs += __shfl_xor(rs, 32);
    const bool grew = !__all(mn == m);
    l = l * al + rs;
    m = mn;
    if (grew) {  // wave-uniform: skip o-rescale when no lane's max moved
#pragma unroll
      for (int r = 0; r < 4; r++) {
        const int src = (lane & 48) + quad * 4 + r;  // same quad, l16 = quad*4+r
        const float ab = __shfl(al, src);
#pragma unroll
        for (int j = 0; j < 8; j++) o[j][r] *= ab;
      }
    }
  };

  auto pv = [&](f32x4 (&o)[8], const unsigned short* vBuf) {
#pragma unroll
    for (int ks = 0; ks < 2; ks++) {
      const int cs = (((ks * 4 + quad) ^ (l16 & 7)) << 3);
      const bf16x8 pf = *(const bf16x8*)&sPw[l16 * 64 + cs];
#pragma unroll
      for (int j = 0; j < 8; j++) {
        const bf16x8 vf = *(const bf16x8*)&vBuf[(j * 16 + l16) * 64 + cs];
        o[j] = MFMA_BF16(pf, vf, o[j]);
      }
    }
  };

  auto compute_tile = [&](int kt, const unsigned short* kBuf,
                          const unsigned short* vBuf) {
    const int k0 = kt << 6;
    f32x4 st[4];
#pragma unroll
    for (int ni = 0; ni < 4; ni++) st[ni] = f32x4{0.f, 0.f, 0.f, 0.f};
#pragma unroll
    for (int ds = 0; ds < 4; ds++) {
#pragma unroll
      for (int ni = 0; ni < 4; ni++) {
        const bf16x8 kf =
            *(const bf16x8*)&kBuf[(ni * 16 + l16) * 128 + (((ds * 4 + quad) ^ l16) << 3)];
        st[ni] = MFMA_BF16(kf, qf[ds], st[ni]);
      }
    }

    if (kt == qt) {  // diagonal: fork masked stats, dual update
      m1 = m2; l1 = l2;
#pragma unroll
      for (int j = 0; j < 8; j++) o1[j] = o2[j];
      softmax_update(m1, l1, o1, st, true, k0);
      pv(o1, vBuf);
    }
    softmax_update(m2, l2, o2, st, false, k0);
    pv(o2, vBuf);
  };

  // pipelined K-loop: stage(kt+1) issues right after the barrier that
  // drained stage(kt); compute(kt) hides the latency.
  stageKV(0, sK0, sV0);
  for (int kt2 = 0; kt2 < 32; kt2 += 2) {
    __syncthreads();                       // drains stage(kt2) [buf0]
    if (kt2 + 1 < 32) stageKV(kt2 + 1, sK1, sV1);
    compute_tile(kt2, sK0, sV0);
    __syncthreads();                       // drains stage(kt2+1) [buf1]
    if (kt2 + 2 < 32) stageKV(kt2 + 2, sK0, sV0);
    compute_tile(kt2 + 1, sK1, sV1);
  }

  // in-register ring combine: 1x masked + (ws-1)x unmasked (log2 domain)
  const float fws = (float)(wsp[0] - 1);
  const float a = exp2f(m1 - m2);
  const float se = l1 * a + fws * l2;
  const float inv = 1.0f / (se + 1e-8f);
  const float f1 = (a / (l1 + 1e-8f)) * inv;
  const float f2 = (fws / (l2 + 1e-8f)) * inv;
#pragma unroll
  for (int r = 0; r < 4; r++) {
    const int src = (lane & 48) + quad * 4 + r;  // same quad, l16 = quad*4+r
    const float f1b = __shfl(f1, src);
    const float f2b = __shfl(f2, src);
    const int row = qt * 64 + wave * 16 + quad * 4 + r;
#pragma unroll
    for (int j = 0; j < 8; j++) {
      const float ov = o1[j][r] * f1b + o2[j][r] * f2b;
      O[(size_t)row * 2048 + h * 128 + j * 16 + l16] = f2bf(ov);
    }
  }
}

// ------------------------------ O-proj GEMM --------------------------------
// out[2048 x 2048] fp32 = attn[2048 x 2048]bf16 * ow[2048 x 2048]^T + ob
// 64x128 tile, BK=128 (16 iters), chunk-XOR swizzle on 16-chunk rows.
__global__ __launch_bounds__(256) void gemm_o(
    const unsigned short* __restrict__ A, const unsigned short* __restrict__ Bt,
    const float* __restrict__ ob, float* __restrict__ Cout) {
  __shared__ __align__(16) unsigned short sA[64 * 128];
  __shared__ __align__(16) unsigned short sB[128 * 128];
  const int tid = threadIdx.x;
  const int wave = tid >> 6, lane = tid & 63;
  const int quad = lane >> 4, l16 = lane & 15;
  const int wm = wave >> 1, wn = wave & 1;
  const int m0 = blockIdx.y << 6, n0 = blockIdx.x << 7;

  f32x4 acc[2][4] = {};

  for (int k0 = 0; k0 < 2048; k0 += 128) {
    __syncthreads();
#pragma unroll
    for (int t = 0; t < 4; t++) {
      const int i = t * 4 + wave;
      const int idx = i * 64 + lane;
      const int row = idx >> 4;
      const int c = (idx & 15) ^ (row & 15);
      load16_lds(A + (size_t)(m0 + row) * 2048 + k0 + c * 8, &sA[i * 512]);
    }
#pragma unroll
    for (int t = 0; t < 8; t++) {
      const int i = t * 4 + wave;
      const int idx = i * 64 + lane;
      const int row = idx >> 4;
      const int c = (idx & 15) ^ (row & 15);
      load16_lds(Bt + (size_t)(n0 + row) * 2048 + k0 + c * 8, &sB[i * 512]);
    }
    __syncthreads();
#pragma unroll
    for (int ks = 0; ks < 4; ks++) {
      const int cs = ((ks * 4 + quad) ^ l16) << 3;
      bf16x8 af[2], bfr[4];
#pragma unroll
      for (int i = 0; i < 2; i++)
        af[i] = *(const bf16x8*)&sA[(wm * 32 + i * 16 + l16) * 128 + cs];
#pragma unroll
      for (int i = 0; i < 4; i++)
        bfr[i] = *(const bf16x8*)&sB[(wn * 64 + i * 16 + l16) * 128 + cs];
#pragma unroll
      for (int mi = 0; mi < 2; mi++)
#pragma unroll
        for (int ni = 0; ni < 4; ni++)
          acc[mi][ni] = MFMA_BF16(af[mi], bfr[ni], acc[mi][ni]);
    }
  }

#pragma unroll
  for (int mi = 0; mi < 2; mi++) {
    const int row = m0 + wm * 32 + mi * 16 + quad * 4;
#pragma unroll
    for (int ni = 0; ni < 4; ni++) {
      const int col = n0 + wn * 64 + ni * 16 + l16;
#pragma unroll
      for (int r = 0; r < 4; r++) {
        Cout[(size_t)(row + r) * 2048 + col] = acc[mi][ni][r] + ob[col];
      }
    }
  }
}

// ------------------------------- launcher ----------------------------------
extern "C" void kernel_launch(void* const* d_in, const int* in_sizes, int n_in,
                              void* d_out, int out_size, void* d_ws, size_t ws_size,
                              hipStream_t stream) {
  (void)in_sizes; (void)n_in; (void)out_size; (void)ws_size;
  const float* hs = (const float*)d_in[0];
  const float* qw = (const float*)d_in[1];
  const float* qb = (const float*)d_in[2];
  const float* kw = (const float*)d_in[3];
  const float* kb = (const float*)d_in[4];
  const float* vw = (const float*)d_in[5];
  const float* vb = (const float*)d_in[6];
  const float* ow = (const float*)d_in[7];
  const float* ob = (const float*)d_in[8];
  const int* wsz = (const int*)d_in[9];

  char* w = (char*)d_ws;
  unsigned short* hsb  = (unsigned short*)(w + 0);          //  8 MB (S,HID) bf16
  unsigned short* wqkv = (unsigned short*)(w + 8388608);    // 24 MB (6144,2048) bf16
  unsigned short* owb  = (unsigned short*)(w + 33554432);   //  8 MB
  unsigned short* Qb_  = (unsigned short*)(w + 41943040);   //  8 MB (H,S,D)
  unsigned short* Kb_  = (unsigned short*)(w + 50331648);   //  8 MB (H,S,D)
  unsigned short* Vtb  = (unsigned short*)(w + 58720256);   //  8 MB (H,D,S)
  unsigned short* atb  = (unsigned short*)(w + 67108864);   //  8 MB (S,H*D)

  cvt_all<<<20480, 256, 0, stream>>>(
      (const float4*)hs, (const float4*)qw, (const float4*)kw, (const float4*)vw,
      (const float4*)ow,
      (ushort4*)hsb, (ushort4*)wqkv, (ushort4*)(wqkv + 4194304),
      (ushort4*)(wqkv + 8388608), (ushort4*)owb);

  gemm_qkv<<<dim3(48, 16), 256, 0, stream>>>(hsb, wqkv, qb, kb, vb, Qb_, Kb_, Vtb);
  attn_fwd<<<dim3(32, 16), 256, 0, stream>>>(Qb_, Kb_, Vtb, atb, wsz);
  gemm_o<<<dim3(16, 32), 256, 0, stream>>>(atb, owb, ob, (float*)d_out);
}